// Round 6
// baseline (322.330 us; speedup 1.0000x reference)
//
#include <hip/hip_runtime.h>
#include <hip/hip_bf16.h>
#include <cstdint>
#include <cstddef>

#define N_NODES 100000
#define N_EDGES 1600000
#define F_IN 256
#define F_OUT 128

#define NB 782        // buckets = row >> 7 (128 rows each)
#define NBLK 196      // tiles for bucket_hist/scatter
#define TILE 8192     // edges per tile
#define CAP 4096      // max edges staged per bucket (avg 2048, sigma 45)
#define META2_CAP 2400000   // padded CSR capacity (worst case 1.6M + 100K*7)

typedef __attribute__((ext_vector_type(8))) short short8;
typedef __attribute__((ext_vector_type(4))) float floatx4;

static __device__ __forceinline__ unsigned short f2bf(float f) {
    union { float f; unsigned u; } v; v.f = f;
    unsigned r = v.u + 0x7FFF + ((v.u >> 16) & 1);   // RNE
    return (unsigned short)(r >> 16);
}

// ---- w prep: fp32 [K=256][N=128] -> bf16 B-frag-contiguous layout ----------
// wT2 element (k, n) stored at (k>>3)*1024 + n*8 + (k&7): each (k-group, n)
// 8-elem frag is 16 B contiguous; a wave's B-frag load is 4x256 B segments.
// Also zeroes bucket_total[0..NB] (incl. the padded-CSR allocator at [NB]).
__global__ void prep_w(const float* __restrict__ w, unsigned short* __restrict__ wT2,
                       int* __restrict__ bucket_total) {
    int i = blockIdx.x * 256 + threadIdx.x;   // 0..32767
    if (i <= NB) bucket_total[i] = 0;
    int k = i >> 7;
    int n = i & 127;
    wT2[(k >> 3) * 1024 + n * 8 + (k & 7)] = f2bf(w[i]);
}

// ---- GEMM: h[100000][128] (bf16) = x (fp32) @ w, no LDS --------------------
// 128 rows/block, 32 rows/wave (2 m-frags x 8 n-frags). B-frags direct from
// global (w = 64 KB, L1/L2-hot). ~3 waves/SIMD vs 2 blocks/CU with LDS.
__global__ __launch_bounds__(256) void gemm_xw(const float* __restrict__ x,
                                               const unsigned short* __restrict__ wT2,
                                               unsigned short* __restrict__ h) {
    const int tid = threadIdx.x;
    const int wave = tid >> 6, lane = tid & 63;
    const int quad = lane >> 4, l16 = lane & 15;
    const int rowbase = blockIdx.x * 128 + wave * 32;

    floatx4 acc[2][8];
    #pragma unroll
    for (int mf = 0; mf < 2; mf++)
        #pragma unroll
        for (int nt = 0; nt < 8; nt++) acc[mf][nt] = (floatx4)0.f;

    #pragma unroll
    for (int ks = 0; ks < 8; ks++) {
        const int k0 = ks * 32 + quad * 8;
        short8 afrag[2];
        #pragma unroll
        for (int mf = 0; mf < 2; mf++) {
            int row = rowbase + mf * 16 + l16;
            if (row >= N_NODES) row = N_NODES - 1;
            const float* xp = x + (size_t)row * F_IN + k0;
            floatx4 x0 = *reinterpret_cast<const floatx4*>(xp);
            floatx4 x1 = *reinterpret_cast<const floatx4*>(xp + 4);
            short8 a;
            a[0] = (short)f2bf(x0[0]); a[1] = (short)f2bf(x0[1]);
            a[2] = (short)f2bf(x0[2]); a[3] = (short)f2bf(x0[3]);
            a[4] = (short)f2bf(x1[0]); a[5] = (short)f2bf(x1[1]);
            a[6] = (short)f2bf(x1[2]); a[7] = (short)f2bf(x1[3]);
            afrag[mf] = a;
        }
        short8 bfrag[8];
        const unsigned short* bp = wT2 + (size_t)(ks * 4 + quad) * 1024 + l16 * 8;
        #pragma unroll
        for (int nt = 0; nt < 8; nt++)
            bfrag[nt] = *reinterpret_cast<const short8*>(bp + nt * 128);
        #pragma unroll
        for (int mf = 0; mf < 2; mf++)
            #pragma unroll
            for (int nt = 0; nt < 8; nt++)
                acc[mf][nt] = __builtin_amdgcn_mfma_f32_16x16x32_bf16(
                    afrag[mf], bfrag[nt], acc[mf][nt], 0, 0, 0);
    }

    // C/D: col = l16, row = quad*4 + reg
    #pragma unroll
    for (int mf = 0; mf < 2; mf++) {
        const int mbase = rowbase + mf * 16 + quad * 4;
        #pragma unroll
        for (int reg = 0; reg < 4; reg++) {
            const int m = mbase + reg;
            if (m < N_NODES) {
                #pragma unroll
                for (int nt = 0; nt < 8; nt++)
                    h[(size_t)m * F_OUT + nt * 16 + l16] = f2bf(acc[mf][nt][reg]);
            }
        }
    }
}

// ---- CSR build via 2-level bucket sort (no per-edge global atomics) --------
__global__ __launch_bounds__(256) void bucket_hist(const int* __restrict__ row,
                                                   int* __restrict__ bucket_total,
                                                   int* __restrict__ blockbase) {
    __shared__ int hist[NB];
    const int t = threadIdx.x, blk = blockIdx.x;
    for (int i = t; i < NB; i += 256) hist[i] = 0;
    __syncthreads();
    const long tb = (long)blk * TILE;
    #pragma unroll
    for (int c = 0; c < 8; c++) {
        long i0 = tb + c * 1024 + t * 4;
        if (i0 + 4 <= N_EDGES) {
            int4 r = *reinterpret_cast<const int4*>(row + i0);
            atomicAdd(&hist[r.x >> 7], 1); atomicAdd(&hist[r.y >> 7], 1);
            atomicAdd(&hist[r.z >> 7], 1); atomicAdd(&hist[r.w >> 7], 1);
        } else {
            for (long i = i0; i < N_EDGES && i < i0 + 4; i++)
                atomicAdd(&hist[row[i] >> 7], 1);
        }
    }
    __syncthreads();
    for (int bin = t; bin < NB; bin += 256)
        blockbase[bin * NBLK + blk] = atomicAdd(&bucket_total[bin], hist[bin]);
}

__global__ void bucket_scan(const int* __restrict__ bucket_total,
                            int* __restrict__ bucket_base) {
    __shared__ int sm[1024];
    const int t = threadIdx.x;
    int v = (t < NB) ? bucket_total[t] : 0;
    sm[t] = v; __syncthreads();
    for (int off = 1; off < 1024; off <<= 1) {
        int x2 = (t >= off) ? sm[t - off] : 0;
        __syncthreads();
        sm[t] += x2;
        __syncthreads();
    }
    if (t < NB) bucket_base[t] = sm[t] - v;
    if (t == NB - 1) bucket_base[NB] = sm[t];
}

__global__ __launch_bounds__(256) void bucket_scatter(const int* __restrict__ row,
                                                      const int* __restrict__ col,
                                                      const float* __restrict__ val,
                                                      const int* __restrict__ bucket_base,
                                                      const int* __restrict__ blockbase,
                                                      int2* __restrict__ metabuf) {
    __shared__ int sbase[NB];
    const int t = threadIdx.x, blk = blockIdx.x;
    for (int bin = t; bin < NB; bin += 256)
        sbase[bin] = bucket_base[bin] + blockbase[bin * NBLK + blk];
    __syncthreads();
    const long tb = (long)blk * TILE;
    #pragma unroll
    for (int c = 0; c < 8; c++) {
        long i0 = tb + c * 1024 + t * 4;
        if (i0 + 4 <= N_EDGES) {
            int4 r  = *reinterpret_cast<const int4*>(row + i0);
            int4 cc = *reinterpret_cast<const int4*>(col + i0);
            floatx4 vv = *reinterpret_cast<const floatx4*>(val + i0);
            int rr[4] = {r.x, r.y, r.z, r.w};
            int c4[4] = {cc.x, cc.y, cc.z, cc.w};
            float v4[4] = {vv[0], vv[1], vv[2], vv[3]};
            #pragma unroll
            for (int j = 0; j < 4; j++) {
                int bin = rr[j] >> 7, rl = rr[j] & 127;
                int pos = atomicAdd(&sbase[bin], 1);
                metabuf[pos] = make_int2(c4[j] | (rl << 24), __float_as_int(v4[j]));
            }
        } else {
            for (long i = i0; i < N_EDGES && i < i0 + 4; i++) {
                int rv = row[i];
                int bin = rv >> 7, rl = rv & 127;
                int pos = atomicAdd(&sbase[bin], 1);
                metabuf[pos] = make_int2(col[i] | (rl << 24), __float_as_int(val[i]));
            }
        }
    }
}

// per-bucket: 128-bin hist+scan of PADDED sizes (pad each row to mult of 8
// with (col=0,val=0) so spmm needs zero clamps), one global atomic per block
// allocates padded space in meta2; write row_desc = (start, niter=pad/8).
__global__ __launch_bounds__(256) void csr_pad(const int* __restrict__ bucket_base,
                                               const int2* __restrict__ metabuf,
                                               int* __restrict__ alloc,
                                               int2* __restrict__ meta2,
                                               int2* __restrict__ row_desc) {
    __shared__ int2 st[CAP];
    __shared__ int hist[128], scanb[128], cursor[128];
    __shared__ int sbase_sh;
    const int t = threadIdx.x, b = blockIdx.x;
    const int b0 = bucket_base[b], e = bucket_base[b + 1];
    int n = e - b0; if (n > CAP) n = CAP;
    if (t < 128) hist[t] = 0;
    __syncthreads();
    for (int i = t; i < n; i += 256) {
        int2 w = metabuf[b0 + i];
        st[i] = w;
        atomicAdd(&hist[((unsigned)w.x >> 24) & 127], 1);
    }
    __syncthreads();
    if (t < 128) scanb[t] = (hist[t] + 7) & ~7;   // padded size
    __syncthreads();
    for (int off = 1; off < 128; off <<= 1) {
        int v = (t >= off && t < 128) ? scanb[t - off] : 0;
        __syncthreads();
        if (t < 128) scanb[t] += v;
        __syncthreads();
    }
    if (t == 127) sbase_sh = atomicAdd(alloc, scanb[127]);
    __syncthreads();
    if (t < 128) {
        int c = hist[t], p = (c + 7) & ~7;
        int base_row = sbase_sh + scanb[t] - p;
        cursor[t] = base_row;
        int r = b * 128 + t;
        if (r < N_NODES) row_desc[r] = make_int2(base_row, p >> 3);
        for (int k = c; k < p; k++) meta2[base_row + k] = make_int2(0, 0);
    }
    __syncthreads();
    for (int i = t; i < n; i += 256) {
        int2 w = st[i];
        int rl = ((unsigned)w.x >> 24) & 127;
        int pos = atomicAdd(&cursor[rl], 1);
        meta2[pos] = make_int2(w.x & 0x00FFFFFF, w.y);
    }
}

// ---- SpMM gather: 2 rows/wave, 8 edges/row/iter, zero inner conditionals ---
// half = g>>1 picks the row; gi = g&1 picks edges it*8+gi*4+u. Padded meta2
// means no clamps/predication. Epilogue: one shfl_xor(16), float4 store.
__global__ __launch_bounds__(256) void spmm(const unsigned short* __restrict__ h,
                                            const int2* __restrict__ row_desc,
                                            const int2* __restrict__ meta,
                                            const float* __restrict__ bias,
                                            float* __restrict__ out) {
    const int wave = threadIdx.x >> 6, lane = threadIdx.x & 63;
    const int g = lane >> 4, l16 = lane & 15;
    const int gi = g & 1;
    const int r = blockIdx.x * 8 + wave * 2 + (g >> 1);
    const int2 d = row_desc[r];
    const int start = d.x, niter = d.y;

    float acc[8];
    #pragma unroll
    for (int k = 0; k < 8; k++) acc[k] = 0.f;

    const unsigned short* hp = h + l16 * 8;
    const int2* mp = meta + start + gi * 4;

    for (int it = 0; it < niter; ++it) {
        int2 mm[4];
        #pragma unroll
        for (int u = 0; u < 4; u++) mm[u] = mp[it * 8 + u];
        uint4 hv[4];
        #pragma unroll
        for (int u = 0; u < 4; u++)
            hv[u] = *reinterpret_cast<const uint4*>(hp + (size_t)mm[u].x * F_OUT);
        #pragma unroll
        for (int u = 0; u < 4; u++) {
            float v = __int_as_float(mm[u].y);
            #pragma unroll
            for (int dd = 0; dd < 4; dd++) {
                unsigned uu = ((const unsigned*)&hv[u])[dd];
                acc[2 * dd]     += v * __uint_as_float(uu << 16);
                acc[2 * dd + 1] += v * __uint_as_float(uu & 0xffff0000u);
            }
        }
    }

    #pragma unroll
    for (int k = 0; k < 8; k++) acc[k] += __shfl_xor(acc[k], 16);

    const int ch = l16 * 8 + gi * 4;
    float4 bv = *reinterpret_cast<const float4*>(bias + ch);
    float o0 = fmaxf((gi ? acc[4] : acc[0]) + bv.x, 0.f);
    float o1 = fmaxf((gi ? acc[5] : acc[1]) + bv.y, 0.f);
    float o2 = fmaxf((gi ? acc[6] : acc[2]) + bv.z, 0.f);
    float o3 = fmaxf((gi ? acc[7] : acc[3]) + bv.w, 0.f);
    float4 o; o.x = o0; o.y = o1; o.z = o2; o.w = o3;
    *reinterpret_cast<float4*>(out + (size_t)r * F_OUT + ch) = o;
}

extern "C" void kernel_launch(void* const* d_in, const int* in_sizes, int n_in,
                              void* d_out, int out_size, void* d_ws, size_t ws_size,
                              hipStream_t stream) {
    const float* x        = (const float*)d_in[0];
    const int*   adj_row  = (const int*)d_in[1];
    const int*   adj_col  = (const int*)d_in[2];
    const float* adj_vals = (const float*)d_in[3];
    const float* w        = (const float*)d_in[4];
    const float* b        = (const float*)d_in[5];
    float* out = (float*)d_out;

    // workspace layout (16B-aligned); total ~59 MB
    char* ws = (char*)d_ws;
    unsigned short* wT2 = (unsigned short*)ws;                          // 64 KB
    unsigned short* h   = (unsigned short*)(ws + 65536);                // 25.6 MB
    size_t off = 65536 + (size_t)N_NODES * F_OUT * 2;
    int2* metabuf  = (int2*)(ws + off);   off += (size_t)N_EDGES * 8;   // 12.8 MB
    int2* meta2    = (int2*)(ws + off);   off += (size_t)META2_CAP * 8; // 19.2 MB
    int2* row_desc = (int2*)(ws + off);   off += (size_t)100096 * 8;    // 0.8 MB
    int* blockbase = (int*)(ws + off);    off += (size_t)NB * NBLK * 4; // 613 KB
    int* bucket_total = (int*)(ws + off); off += 4096;   // [NB] = alloc counter
    int* bucket_base  = (int*)(ws + off); off += 4096;

    prep_w<<<128, 256, 0, stream>>>(w, wT2, bucket_total);
    gemm_xw<<<782, 256, 0, stream>>>(x, wT2, h);
    bucket_hist<<<NBLK, 256, 0, stream>>>(adj_row, bucket_total, blockbase);
    bucket_scan<<<1, 1024, 0, stream>>>(bucket_total, bucket_base);
    bucket_scatter<<<NBLK, 256, 0, stream>>>(adj_row, adj_col, adj_vals,
                                             bucket_base, blockbase, metabuf);
    csr_pad<<<NB, 256, 0, stream>>>(bucket_base, metabuf, bucket_total + NB,
                                    meta2, row_desc);
    spmm<<<12500, 256, 0, stream>>>(h, row_desc, meta2, b, out);
}